// Round 1
// baseline (73.428 us; speedup 1.0000x reference)
//
#include <hip/hip_runtime.h>

// Problem constants (B=64, IN=1024, UNITS=1024, BITS=8)
#define IN_F   1024
#define UNITS  1024
#define BDIM   64
#define NCH    8            // i-chunks (reduction split)
#define CHUNK  128          // IN_F / NCH
#define BG     4            // b-values per thread / per block

// Math: out[b,j] = relu(bias[j] + sum_i trunc(x[b,i] * K[i,j] / 256))
// (exact collapse of the reference's 4-round base-4 digit loop; all values
// are exact integers in fp32, so this is bit-exact.)

__global__ __launch_bounds__(256) void partial_kernel(
    const float* __restrict__ x, const float* __restrict__ K,
    float* __restrict__ ws)
{
    const int bid = blockIdx.x;          // 512 blocks
    const int jt = bid & 3;              // 4 j-tiles of 256
    const int bg = (bid >> 2) & 15;      // 16 b-groups of 4
    const int ic = bid >> 6;             // 8 i-chunks of 128
    const int tid = threadIdx.x;
    const int j  = jt * 256 + tid;
    const int b0 = bg * BG;
    const int i0 = ic * CHUNK;

    // x tile, pre-scaled by 1/256, transposed to [i][b] for ds_read_b128
    __shared__ float xs[CHUNK * BG];     // 512 floats = 2 KB
    for (int t = tid; t < CHUNK * BG; t += 256) {
        const int bb = t >> 7;           // 0..3
        const int ii = t & 127;          // 0..127 (coalesced along i)
        xs[ii * BG + bb] = x[(b0 + bb) * IN_F + i0 + ii] * (1.0f / 256.0f);
    }
    __syncthreads();

    float acc0 = 0.f, acc1 = 0.f, acc2 = 0.f, acc3 = 0.f;
    const float* kp = K + (size_t)i0 * UNITS + j;
#pragma unroll 8
    for (int i = 0; i < CHUNK; ++i) {
        const float k = kp[(size_t)i * UNITS];          // coalesced dword
        const float4 xv = *(const float4*)&xs[i * BG];  // broadcast b128
        acc0 += truncf(xv.x * k);
        acc1 += truncf(xv.y * k);
        acc2 += truncf(xv.z * k);
        acc3 += truncf(xv.w * k);
    }

    // partials: ws[ic][b][j]
    float* wp = ws + ((size_t)ic * BDIM + b0) * UNITS + j;
    wp[0 * UNITS] = acc0;
    wp[1 * UNITS] = acc1;
    wp[2 * UNITS] = acc2;
    wp[3 * UNITS] = acc3;
}

__global__ __launch_bounds__(256) void reduce_kernel(
    const float* __restrict__ ws, const float* __restrict__ bias,
    float* __restrict__ out)
{
    const int idx = blockIdx.x * 256 + threadIdx.x;  // 16384 float4 groups
    const int j4 = idx & 255;                        // 256 float4 per j-row
    const int b  = idx >> 8;

    const float4* p = (const float4*)ws + (size_t)b * (UNITS / 4) + j4;
    float4 s = make_float4(0.f, 0.f, 0.f, 0.f);
#pragma unroll
    for (int c = 0; c < NCH; ++c) {
        const float4 v = p[(size_t)c * BDIM * (UNITS / 4)];
        s.x += v.x; s.y += v.y; s.z += v.z; s.w += v.w;
    }
    const float4 bv = ((const float4*)bias)[j4];
    s.x = fmaxf(s.x + bv.x, 0.f);
    s.y = fmaxf(s.y + bv.y, 0.f);
    s.z = fmaxf(s.z + bv.z, 0.f);
    s.w = fmaxf(s.w + bv.w, 0.f);
    ((float4*)out)[idx] = s;
}

extern "C" void kernel_launch(void* const* d_in, const int* in_sizes, int n_in,
                              void* d_out, int out_size, void* d_ws, size_t ws_size,
                              hipStream_t stream) {
    const float* x    = (const float*)d_in[0];  // (64, 1024)
    const float* K    = (const float*)d_in[1];  // (1024, 1024)
    const float* bias = (const float*)d_in[2];  // (1024,)
    // d_in[3] = bits (always 8)
    float* out = (float*)d_out;                 // (64, 1024)
    float* ws  = (float*)d_ws;                  // needs NCH*B*UNITS*4 = 2 MB

    partial_kernel<<<512, 256, 0, stream>>>(x, K, ws);
    reduce_kernel<<<64, 256, 0, stream>>>(ws, bias, out);
}